// Round 5
// baseline (435.575 us; speedup 1.0000x reference)
//
#include <hip/hip_runtime.h>
#include <hip/hip_bf16.h>

// Problem constants (B,T,S,D = 32,1024,1024,512)
#define B_ 32
#define T_ 1024
#define S_ 1024
#define D_ 512
#define M_ (B_*T_)       // 32768 GEMM rows
#define N_ D_            // 512  GEMM cols
#define K_ (2*D_)        // 1024 GEMM reduction

typedef __attribute__((ext_vector_type(8))) short bf16x8;  // 8 bf16 = 4 VGPRs
typedef __attribute__((ext_vector_type(4))) float f32x4;

__device__ inline unsigned short f2bf(float x) {
    union { float f; unsigned u; } v; v.f = x;
    unsigned r = v.u + 0x7FFFu + ((v.u >> 16) & 1u);   // RNE
    return (unsigned short)(r >> 16);
}

// pack 2 f32 -> 2 bf16 (RNE), packed in 32 bits
__device__ inline unsigned cvt2bf(float lo, float hi) {
#if __has_builtin(__builtin_amdgcn_cvt_pk_bf16_f32)
    typedef __attribute__((ext_vector_type(2))) __bf16 bf2;
    union { bf2 v; unsigned u; } r;
    r.v = __builtin_amdgcn_cvt_pk_bf16_f32(lo, hi);
    return r.u;
#else
    return (unsigned)f2bf(lo) | ((unsigned)f2bf(hi) << 16);
#endif
}

// fast tanh: 1 - 2/(e^{2x}+1) via hw exp2 + rcp. rel err ~1e-7, exact sat at +-1.
__device__ inline float fast_tanh(float x) {
#if __has_builtin(__builtin_amdgcn_exp2f) && __has_builtin(__builtin_amdgcn_rcpf)
    const float e = __builtin_amdgcn_exp2f(x * 2.885390082f);   // e^{2x}
    const float r = __builtin_amdgcn_rcpf(e + 1.0f);
    return 1.0f - 2.0f * r;
#else
    return tanhf(x);
#endif
}

// ---------------------------------------------------------------------------
// Kernel 1: alignment scan -> jbuf.
// ---------------------------------------------------------------------------
__global__ void align_kernel(const int* __restrict__ iv, int* __restrict__ jbuf) {
    const int b = blockIdx.x;          // 32 blocks x 64 threads
    const int lane = threadIdx.x;      // 16 tokens per lane
    const int* row = iv + b * T_;
    int f[16];
    int local = 0;
    const int t0 = lane * 16;
    #pragma unroll
    for (int q = 0; q < 16; ++q) {
        const int t = t0 + q;
        const int tok = row[t];
        const int fl = (t > 0 && (tok == 1 || tok == 2)) ? 1 : 0;
        f[q] = fl;
        local += fl;
    }
    int incl = local;
    #pragma unroll
    for (int off = 1; off < 64; off <<= 1) {
        const int up = __shfl_up(incl, off, 64);
        if (lane >= off) incl += up;
    }
    int run = incl - local;            // exclusive prefix at this lane's first token
    #pragma unroll
    for (int q = 0; q < 16; ++q) {
        const int t = t0 + q;
        run += f[q];
        int j;
        if (t == 0) {
            j = 0;                     // attn[b,0,0] = 1 always
        } else {
            j = t - run - 1;
            if (j < 0) j += S_;        // torch negative-index wrap
        }
        jbuf[b * T_ + t] = j;
    }
}

// ---------------------------------------------------------------------------
// Kernel 2: W [512,1024] f32 -> bf16
// ---------------------------------------------------------------------------
__global__ void pack_w(const float* __restrict__ W, unsigned short* __restrict__ Wbf) {
    const int idx = blockIdx.x * blockDim.x + threadIdx.x;   // N_*K_/8 threads
    const f32x4 a = ((const f32x4*)W)[idx * 2];
    const f32x4 c = ((const f32x4*)W)[idx * 2 + 1];
    union { bf16x8 v; unsigned u[4]; } pk;
    pk.u[0] = cvt2bf(a[0], a[1]); pk.u[1] = cvt2bf(a[2], a[3]);
    pk.u[2] = cvt2bf(c[0], c[1]); pk.u[3] = cvt2bf(c[2], c[3]);
    *(bf16x8*)(Wbf + (size_t)idx * 8) = pk.v;
}

// ---------------------------------------------------------------------------
// Kernel 3 (heterogeneous): blocks [0,512) = attn one-hot (dispatched first);
// [512, 1536) = GEMM tiles, BM=128 x BN=128.
//
// R10 = R8's counted-vmcnt pipeline (proven: raises issue rate to 3.8 TB/s)
//     + R9's sibling-adjacent same-XCD dispatch map (proven: FETCH 74 MB).
// The ONLY change vs R8 is the map: the 4 bn-siblings of each bm-panel sit
// 8 dispatch slots apart (same XCD, hw round-robins blockIdx%8) within 24
// slots -> in phase + same L2 regardless of pipeline drift or generations.
//
// K-loop per sub-iter:
//   MFMA(i)                      // reads As/Bs
//   s_barrier                    // reads done -> safe to overwrite
//   DMA_B(i+1)  [4 loads]        // global_load_lds, oldest outstanding
//   LOAD_A(i+2) [8 loads] ->regs // stays IN FLIGHT across the next barrier
//   STAGE_A(i+1)                 // compiler waits A(i+1) regs only
//   s_waitcnt vmcnt(8) lgkm(0)   // drains B(i+1)+ds_writes, keeps A(i+2)
//   s_barrier
// ---------------------------------------------------------------------------
#define BM 128
#define BN 128
#define BK 64
#define NIT (K_ / BK)                    // 16
#define KMAX (K_ - BK)                   // 960
#define NGEMM ((M_ / BM) * (N_ / BN))    // 1024
#define NATTN 512                        // 64 rows each

__global__ __launch_bounds__(256, 4)
void gemm_attn(const unsigned short* __restrict__ Wbf,
               const float* __restrict__ bias,
               float* __restrict__ out,
               float* __restrict__ attn,
               const float* __restrict__ ctx,
               const float* __restrict__ outp,
               const int* __restrict__ jbuf) {
    const int bx = blockIdx.x;
    const int tid = threadIdx.x;

    if (bx < NATTN) {
        // ---------------- attn one-hot: 64 rows per block (R5 verbatim) ----
        const int m0 = bx * 64;
        #pragma unroll 4
        for (int r = 0; r < 64; ++r) {
            const int row = m0 + r;
            const int j = jbuf[row];               // broadcast load
            f32x4 v = {0.f, 0.f, 0.f, 0.f};
            if ((j >> 2) == tid) v[j & 3] = 1.0f;
            ((f32x4*)(attn + (size_t)row * S_))[tid] = v;
        }
        return;
    }

    // ---------------- GEMM tile ----------------
    __shared__ unsigned short As[BM * BK];   // 16 KB
    __shared__ unsigned short Bs[BN * BK];   // 16 KB

    const int gbx  = bx - NATTN;
    const int lane = tid & 63;
    const int wave = tid >> 6;
    const int wm = wave >> 1, wn = wave & 1;     // 2x2 waves -> 64x64 each
    const int l16 = lane & 15, quad = lane >> 4;

    // sibling-adjacent same-XCD map (R9, the one change vs R8): the 4
    // bn-siblings of each bm are spaced 8 apart -> same XCD, <=24 slots apart.
    const int xcd = gbx & 7;
    const int bn  = (gbx >> 3) & 3;              // 4 n-tiles of 128
    const int bm  = ((gbx >> 5) << 3) | xcd;     // 256 m-tiles of 128
    const int mBase = bm * BM;
    const int nBase = bn * BN;

    // A staging: chunk c = it*256+tid, row = it*32 + (tid>>3), kc = tid&7.
    const int kc   = tid & 7;
    const int rsub = tid >> 3;                   // 0..31
    const int sw   = kc ^ (rsub & 7);            // swizzle term, it-invariant
    const float* actx[4];
    const float* aout[4];
    #pragma unroll
    for (int it = 0; it < 4; ++it) {
        const int r = it * 32 + rsub;
        const int m = mBase + r;
        const int jm = jbuf[m];
        actx[it] = ctx + ((size_t)((m >> 10) * S_ + jm)) * D_ + kc * 8;
        aout[it] = outp + (size_t)m * D_ - D_ + kc * 8;     // add ko>=512
    }

    f32x4 acc[4][4] = {};
    f32x4 fa0[4][2], fa1[4][2];

#define LOAD_A(FA, KO) do {                                                    \
    const int _koa = (KO);                                                     \
    _Pragma("unroll")                                                          \
    for (int _it = 0; _it < 4; ++_it) {                                        \
        const float* _src = (_koa < D_) ? (actx[_it] + _koa) : (aout[_it] + _koa); \
        FA[_it][0] = ((const f32x4*)_src)[0];                                  \
        FA[_it][1] = ((const f32x4*)_src)[1];                                  \
    }                                                                          \
} while (0)

#define DMA_B(KO) do {                                                         \
    const int _kob = (KO);                                                     \
    _Pragma("unroll")                                                          \
    for (int _it = 0; _it < 4; ++_it) {                                        \
        const int _chunk = _it * 256 + tid;                                    \
        const int _row = _chunk >> 3;                                          \
        const int _kcb = _chunk & 7;                                           \
        const int _gk8 = (_kcb ^ (_row & 7)) * 8;                              \
        const unsigned short* _gB = Wbf + (size_t)(nBase + _row) * K_ + _kob + _gk8; \
        __builtin_amdgcn_global_load_lds(                                      \
            (const __attribute__((address_space(1))) void*)_gB,                \
            (__attribute__((address_space(3))) void*)(&Bs[_chunk * 8]), 16, 0, 0); \
    }                                                                          \
} while (0)

#define STAGE_A(FA) do {                                                       \
    _Pragma("unroll")                                                          \
    for (int _it = 0; _it < 4; ++_it) {                                        \
        union { bf16x8 v; unsigned u[4]; } _pk;                                \
        _pk.u[0] = cvt2bf(FA[_it][0][0], FA[_it][0][1]);                       \
        _pk.u[1] = cvt2bf(FA[_it][0][2], FA[_it][0][3]);                       \
        _pk.u[2] = cvt2bf(FA[_it][1][0], FA[_it][1][1]);                       \
        _pk.u[3] = cvt2bf(FA[_it][1][2], FA[_it][1][3]);                       \
        *(bf16x8*)&As[(_it * 256 + rsub * 8 + sw) * 8] = _pk.v;                \
    }                                                                          \
} while (0)

#define MFMA_PH() do {                                                         \
    _Pragma("unroll")                                                          \
    for (int _ks = 0; _ks < 2; ++_ks) {                                        \
        bf16x8 _af[4], _bfr[4];                                                \
        _Pragma("unroll")                                                      \
        for (int _mt = 0; _mt < 4; ++_mt) {                                    \
            const int _r = wm * 64 + _mt * 16 + l16;                           \
            const int _q = _ks * 4 + quad;                                     \
            _af[_mt] = *(const bf16x8*)&As[(_r * 8 + (_q ^ (_r & 7))) * 8];    \
        }                                                                      \
        _Pragma("unroll")                                                      \
        for (int _nt = 0; _nt < 4; ++_nt) {                                    \
            const int _r = wn * 64 + _nt * 16 + l16;                           \
            const int _q = _ks * 4 + quad;                                     \
            _bfr[_nt] = *(const bf16x8*)&Bs[(_r * 8 + (_q ^ (_r & 7))) * 8];   \
        }                                                                      \
        _Pragma("unroll")                                                      \
        for (int _mt = 0; _mt < 4; ++_mt)                                      \
            _Pragma("unroll")                                                  \
            for (int _nt = 0; _nt < 4; ++_nt)                                  \
                acc[_mt][_nt] = __builtin_amdgcn_mfma_f32_16x16x32_bf16(       \
                    _af[_mt], _bfr[_nt], acc[_mt][_nt], 0, 0, 0);              \
    }                                                                          \
} while (0)

    // -------- prologue: stage tile 0, prefetch A(1) across the barrier -----
    LOAD_A(fa0, 0);                            // A(0)
    DMA_B(0);                                  // B(0)
    __builtin_amdgcn_sched_barrier(0);
    LOAD_A(fa1, BK);                           // A(1), stays in flight
    __builtin_amdgcn_sched_barrier(0);
    STAGE_A(fa0);                              // compiler waits A(0) only
    asm volatile("s_waitcnt vmcnt(8) lgkmcnt(0)" ::: "memory");  // drain B(0)
    __builtin_amdgcn_sched_barrier(0);
    __builtin_amdgcn_s_barrier();

    #pragma unroll 1
    for (int i = 0; i < NIT; i += 2) {
        const int ko = i * BK;
        // ---- even sub-iter: compute tile i, stage tile i+1 ----
        MFMA_PH();
        __builtin_amdgcn_s_barrier();                              // reads done
        DMA_B(ko + BK);                                            // B(i+1)
        __builtin_amdgcn_sched_barrier(0);
        {
            const int _ka = (ko + 2 * BK > KMAX) ? KMAX : ko + 2 * BK;
            LOAD_A(fa0, _ka);                                      // A(i+2)
        }
        __builtin_amdgcn_sched_barrier(0);
        STAGE_A(fa1);                                              // A(i+1) -> As
        asm volatile("s_waitcnt vmcnt(8) lgkmcnt(0)" ::: "memory"); // drain B, keep A(i+2)
        __builtin_amdgcn_sched_barrier(0);
        __builtin_amdgcn_s_barrier();

        // ---- odd sub-iter: compute tile i+1, stage tile i+2 (peeled at end)
        MFMA_PH();
        if (i != NIT - 2) {
            __builtin_amdgcn_s_barrier();
            DMA_B(ko + 2 * BK);                                    // B(i+2)
            __builtin_amdgcn_sched_barrier(0);
            LOAD_A(fa1, ko + 3 * BK);                              // A(i+3), <=KMAX here
            __builtin_amdgcn_sched_barrier(0);
            STAGE_A(fa0);                                          // A(i+2) -> As
            asm volatile("s_waitcnt vmcnt(8) lgkmcnt(0)" ::: "memory");
            __builtin_amdgcn_sched_barrier(0);
            __builtin_amdgcn_s_barrier();
        }
    }

#undef LOAD_A
#undef DMA_B
#undef STAGE_A
#undef MFMA_PH

    // ---- epilogue: fast_tanh(acc + bias), fp32 store (R5 verbatim)
    #pragma unroll
    for (int nt = 0; nt < 4; ++nt) {
        const int n = nBase + wn * 64 + nt * 16 + l16;
        const float bv = bias[n];
        #pragma unroll
        for (int mt = 0; mt < 4; ++mt) {
            #pragma unroll
            for (int r = 0; r < 4; ++r) {
                const int m = mBase + wm * 64 + mt * 16 + quad * 4 + r;
                out[(size_t)m * N_ + n] = fast_tanh(acc[mt][nt][r] + bv);
            }
        }
    }
}

// ---------------------------------------------------------------------------
extern "C" void kernel_launch(void* const* d_in, const int* in_sizes, int n_in,
                              void* d_out, int out_size, void* d_ws, size_t ws_size,
                              hipStream_t stream) {
    const int*   iv   = (const int*)d_in[0];    // input_var [B,T]
    const float* outp = (const float*)d_in[1];  // output   [B,T,D]
    const float* ctx  = (const float*)d_in[2];  // context  [B,S,D]
    // d_in[3] = di (unused by reference body)
    const float* W    = (const float*)d_in[4];  // [D, 2D]
    const float* bias = (const float*)d_in[5];  // [D]

    float* out  = (float*)d_out;                       // [B,T,D]
    float* attn = out + (size_t)M_ * N_;               // [B,T,S]

    // workspace layout: j[M_] int32 | Wbf[N_*K_] bf16   (~1.1 MB total)
    int* jbuf = (int*)d_ws;
    unsigned short* Wbf = (unsigned short*)((char*)d_ws + (size_t)M_ * 4);

    align_kernel<<<B_, 64, 0, stream>>>(iv, jbuf);
    pack_w<<<(N_ * K_ / 8) / 256, 256, 0, stream>>>(W, Wbf);
    gemm_attn<<<NGEMM + NATTN, 256, 0, stream>>>(Wbf, bias, out, attn, ctx, outp, jbuf);
}

// Round 6
// 336.000 us; speedup vs baseline: 1.2964x; 1.2964x over previous
//
#include <hip/hip_runtime.h>
#include <hip/hip_bf16.h>

// Problem constants (B,T,S,D = 32,1024,1024,512)
#define B_ 32
#define T_ 1024
#define S_ 1024
#define D_ 512
#define M_ (B_*T_)       // 32768 GEMM rows
#define N_ D_            // 512  GEMM cols
#define K_ (2*D_)        // 1024 GEMM reduction

typedef __attribute__((ext_vector_type(8))) short bf16x8;  // 8 bf16 = 4 VGPRs
typedef __attribute__((ext_vector_type(4))) float f32x4;

__device__ inline unsigned short f2bf(float x) {
    union { float f; unsigned u; } v; v.f = x;
    unsigned r = v.u + 0x7FFFu + ((v.u >> 16) & 1u);   // RNE
    return (unsigned short)(r >> 16);
}

// pack 2 f32 -> 2 bf16 (RNE), packed in 32 bits
__device__ inline unsigned cvt2bf(float lo, float hi) {
#if __has_builtin(__builtin_amdgcn_cvt_pk_bf16_f32)
    typedef __attribute__((ext_vector_type(2))) __bf16 bf2;
    union { bf2 v; unsigned u; } r;
    r.v = __builtin_amdgcn_cvt_pk_bf16_f32(lo, hi);
    return r.u;
#else
    return (unsigned)f2bf(lo) | ((unsigned)f2bf(hi) << 16);
#endif
}

// fast tanh: 1 - 2/(e^{2x}+1) via hw exp2 + rcp. rel err ~1e-7, exact sat at +-1.
__device__ inline float fast_tanh(float x) {
#if __has_builtin(__builtin_amdgcn_exp2f) && __has_builtin(__builtin_amdgcn_rcpf)
    const float e = __builtin_amdgcn_exp2f(x * 2.885390082f);   // e^{2x}
    const float r = __builtin_amdgcn_rcpf(e + 1.0f);
    return 1.0f - 2.0f * r;
#else
    return tanhf(x);
#endif
}

// ---------------------------------------------------------------------------
// Kernel 1: alignment scan -> jbuf.
// ---------------------------------------------------------------------------
__global__ void align_kernel(const int* __restrict__ iv, int* __restrict__ jbuf) {
    const int b = blockIdx.x;          // 32 blocks x 64 threads
    const int lane = threadIdx.x;      // 16 tokens per lane
    const int* row = iv + b * T_;
    int f[16];
    int local = 0;
    const int t0 = lane * 16;
    #pragma unroll
    for (int q = 0; q < 16; ++q) {
        const int t = t0 + q;
        const int tok = row[t];
        const int fl = (t > 0 && (tok == 1 || tok == 2)) ? 1 : 0;
        f[q] = fl;
        local += fl;
    }
    int incl = local;
    #pragma unroll
    for (int off = 1; off < 64; off <<= 1) {
        const int up = __shfl_up(incl, off, 64);
        if (lane >= off) incl += up;
    }
    int run = incl - local;            // exclusive prefix at this lane's first token
    #pragma unroll
    for (int q = 0; q < 16; ++q) {
        const int t = t0 + q;
        run += f[q];
        int j;
        if (t == 0) {
            j = 0;                     // attn[b,0,0] = 1 always
        } else {
            j = t - run - 1;
            if (j < 0) j += S_;        // torch negative-index wrap
        }
        jbuf[b * T_ + t] = j;
    }
}

// ---------------------------------------------------------------------------
// Kernel 2: W [512,1024] f32 -> bf16
// ---------------------------------------------------------------------------
__global__ void pack_w(const float* __restrict__ W, unsigned short* __restrict__ Wbf) {
    const int idx = blockIdx.x * blockDim.x + threadIdx.x;   // N_*K_/8 threads
    const f32x4 a = ((const f32x4*)W)[idx * 2];
    const f32x4 c = ((const f32x4*)W)[idx * 2 + 1];
    union { bf16x8 v; unsigned u[4]; } pk;
    pk.u[0] = cvt2bf(a[0], a[1]); pk.u[1] = cvt2bf(a[2], a[3]);
    pk.u[2] = cvt2bf(c[0], c[1]); pk.u[3] = cvt2bf(c[2], c[3]);
    *(bf16x8*)(Wbf + (size_t)idx * 8) = pk.v;
}

// ---------------------------------------------------------------------------
// Kernel 3 (heterogeneous): blocks [0,512) = attn one-hot (dispatched first);
// [512, 1536) = GEMM tiles, BM=128 x BN=128.
//
// R11: full-drain K-loop (R5's proven traffic-optimal convoy pacing) with
// A-prefetch placed INSIDE the drain structure:
//   DMA_B(i)                 // B(i) -> LDS DMA
//   STAGE_A(fa)              // cvt A(i): NO WAIT (prefetched last iter)
//   __syncthreads()          // barrier 1: drains B(i)+ds_writes
//   LOAD_A(fa, i+1)          // reuse SAME regs (cvt already read them);
//                            //   flies during the whole MFMA phase
//   MFMA_PH()                // ~600 cy of compute covering the A latency
//   __syncthreads()          // barrier 2: vmcnt(0) drains A(i+1), mostly done
// -> exposed A-latency ~300cy/iter instead of ~900, with ZERO change to the
// pacing semantics (both barriers still fully drain -> no drift, no spill
// games). Single fa buffer keeps arch VGPRs ~100; __launch_bounds__(256,3)
// removes the 128-reg cap that made R7/R8/R10 spill to scratch.
// + R9's sibling-adjacent same-XCD map (proven 74 MB FETCH): 4 bn-siblings
// of each bm sit 8 dispatch slots apart (same XCD) within 24 slots.
// ---------------------------------------------------------------------------
#define BM 128
#define BN 128
#define BK 64
#define KMAX (K_ - BK)                   // 960
#define NGEMM ((M_ / BM) * (N_ / BN))    // 1024
#define NATTN 512                        // 64 rows each

__global__ __launch_bounds__(256, 3)
void gemm_attn(const unsigned short* __restrict__ Wbf,
               const float* __restrict__ bias,
               float* __restrict__ out,
               float* __restrict__ attn,
               const float* __restrict__ ctx,
               const float* __restrict__ outp,
               const int* __restrict__ jbuf) {
    const int bx = blockIdx.x;
    const int tid = threadIdx.x;

    if (bx < NATTN) {
        // ---------------- attn one-hot: 64 rows per block (R5 verbatim) ----
        const int m0 = bx * 64;
        #pragma unroll 4
        for (int r = 0; r < 64; ++r) {
            const int row = m0 + r;
            const int j = jbuf[row];               // broadcast load
            f32x4 v = {0.f, 0.f, 0.f, 0.f};
            if ((j >> 2) == tid) v[j & 3] = 1.0f;
            ((f32x4*)(attn + (size_t)row * S_))[tid] = v;
        }
        return;
    }

    // ---------------- GEMM tile ----------------
    __shared__ unsigned short As[BM * BK];   // 16 KB
    __shared__ unsigned short Bs[BN * BK];   // 16 KB

    const int gbx  = bx - NATTN;
    const int lane = tid & 63;
    const int wave = tid >> 6;
    const int wm = wave >> 1, wn = wave & 1;     // 2x2 waves -> 64x64 each
    const int l16 = lane & 15, quad = lane >> 4;

    // sibling-adjacent same-XCD map (R9-proven): 4 bn-siblings of each bm
    // spaced 8 apart -> same XCD (hw round-robins blockIdx%8), <=24 slots.
    const int xcd = gbx & 7;
    const int bn  = (gbx >> 3) & 3;              // 4 n-tiles of 128
    const int bm  = ((gbx >> 5) << 3) | xcd;     // 256 m-tiles of 128
    const int mBase = bm * BM;
    const int nBase = bn * BN;

    // A staging: chunk c = it*256+tid, row = it*32 + (tid>>3), kc = tid&7.
    const int kc   = tid & 7;
    const int rsub = tid >> 3;                   // 0..31
    const int sw   = kc ^ (rsub & 7);            // swizzle term, it-invariant
    const float* actx[4];
    const float* aout[4];
    #pragma unroll
    for (int it = 0; it < 4; ++it) {
        const int r = it * 32 + rsub;
        const int m = mBase + r;
        const int jm = jbuf[m];
        actx[it] = ctx + ((size_t)((m >> 10) * S_ + jm)) * D_ + kc * 8;
        aout[it] = outp + (size_t)m * D_ - D_ + kc * 8;     // add ko>=512
    }

    f32x4 acc[4][4] = {};
    f32x4 fa[4][2];

#define LOAD_A(KO) do {                                                        \
    const int _koa = (KO);                                                     \
    _Pragma("unroll")                                                          \
    for (int _it = 0; _it < 4; ++_it) {                                        \
        const float* _src = (_koa < D_) ? (actx[_it] + _koa) : (aout[_it] + _koa); \
        fa[_it][0] = ((const f32x4*)_src)[0];                                  \
        fa[_it][1] = ((const f32x4*)_src)[1];                                  \
    }                                                                          \
} while (0)

    // prologue: prefetch A(0); the only fully-exposed A wait is iter 0's cvt.
    LOAD_A(0);

    for (int ko = 0; ko < K_; ko += BK) {
        // ---- 1. B(i) -> LDS DMA (outstanding across the cvt)
        #pragma unroll
        for (int it = 0; it < 4; ++it) {
            const int chunk = it * 256 + tid;
            const int row = chunk >> 3;
            const int kcb = chunk & 7;
            const int gk8 = (kcb ^ (row & 7)) * 8;
            const unsigned short* gB = Wbf + (size_t)(nBase + row) * K_ + ko + gk8;
            __builtin_amdgcn_global_load_lds(
                (const __attribute__((address_space(1))) void*)gB,
                (__attribute__((address_space(3))) void*)(Bs + chunk * 8), 16, 0, 0);
        }
        // ---- 2. cvt + swizzled ds_write_b128; fa was prefetched an iter ago
        #pragma unroll
        for (int it = 0; it < 4; ++it) {
            union { bf16x8 v; unsigned u[4]; } pk;
            pk.u[0] = cvt2bf(fa[it][0][0], fa[it][0][1]);
            pk.u[1] = cvt2bf(fa[it][0][2], fa[it][0][3]);
            pk.u[2] = cvt2bf(fa[it][1][0], fa[it][1][1]);
            pk.u[3] = cvt2bf(fa[it][1][2], fa[it][1][3]);
            *(bf16x8*)&As[(it * 256 + rsub * 8 + sw) * 8] = pk.v;
        }
        __syncthreads();                         // barrier 1: drains B + ds_writes

        // ---- 3. prefetch A(i+1) into the SAME regs (cvt already read them);
        //         flies during the MFMA phase, drained by barrier 2.
        {
            const int ko2 = (ko + BK > KMAX) ? KMAX : ko + BK;   // clamped tail
            LOAD_A(ko2);
        }

        // ---- 4. MFMA phase: 2 K-steps of 32; 16 MFMA each
        #pragma unroll
        for (int ks = 0; ks < 2; ++ks) {
            bf16x8 af[4], bfr[4];
            #pragma unroll
            for (int mt = 0; mt < 4; ++mt) {
                const int r = wm * 64 + mt * 16 + l16;
                const int q = ks * 4 + quad;
                af[mt] = *(const bf16x8*)&As[(r * 8 + (q ^ (r & 7))) * 8];
            }
            #pragma unroll
            for (int nt = 0; nt < 4; ++nt) {
                const int r = wn * 64 + nt * 16 + l16;
                const int q = ks * 4 + quad;
                bfr[nt] = *(const bf16x8*)&Bs[(r * 8 + (q ^ (r & 7))) * 8];
            }
            #pragma unroll
            for (int mt = 0; mt < 4; ++mt)
                #pragma unroll
                for (int nt = 0; nt < 4; ++nt)
                    acc[mt][nt] = __builtin_amdgcn_mfma_f32_16x16x32_bf16(
                        af[mt], bfr[nt], acc[mt][nt], 0, 0, 0);
        }
        __syncthreads();                         // barrier 2: drains A(i+1)
    }

#undef LOAD_A

    // ---- epilogue: fast_tanh(acc + bias), fp32 store (R5 verbatim)
    #pragma unroll
    for (int nt = 0; nt < 4; ++nt) {
        const int n = nBase + wn * 64 + nt * 16 + l16;
        const float bv = bias[n];
        #pragma unroll
        for (int mt = 0; mt < 4; ++mt) {
            #pragma unroll
            for (int r = 0; r < 4; ++r) {
                const int m = mBase + wm * 64 + mt * 16 + quad * 4 + r;
                out[(size_t)m * N_ + n] = fast_tanh(acc[mt][nt][r] + bv);
            }
        }
    }
}

// ---------------------------------------------------------------------------
extern "C" void kernel_launch(void* const* d_in, const int* in_sizes, int n_in,
                              void* d_out, int out_size, void* d_ws, size_t ws_size,
                              hipStream_t stream) {
    const int*   iv   = (const int*)d_in[0];    // input_var [B,T]
    const float* outp = (const float*)d_in[1];  // output   [B,T,D]
    const float* ctx  = (const float*)d_in[2];  // context  [B,S,D]
    // d_in[3] = di (unused by reference body)
    const float* W    = (const float*)d_in[4];  // [D, 2D]
    const float* bias = (const float*)d_in[5];  // [D]

    float* out  = (float*)d_out;                       // [B,T,D]
    float* attn = out + (size_t)M_ * N_;               // [B,T,S]

    // workspace layout: j[M_] int32 | Wbf[N_*K_] bf16   (~1.1 MB total)
    int* jbuf = (int*)d_ws;
    unsigned short* Wbf = (unsigned short*)((char*)d_ws + (size_t)M_ * 4);

    align_kernel<<<B_, 64, 0, stream>>>(iv, jbuf);
    pack_w<<<(N_ * K_ / 8) / 256, 256, 0, stream>>>(W, Wbf);
    gemm_attn<<<NGEMM + NATTN, 256, 0, stream>>>(Wbf, bias, out, attn, ctx, outp, jbuf);
}